// Round 3
// baseline (492.750 us; speedup 1.0000x reference)
//
#include <hip/hip_runtime.h>
#include <hip/hip_bf16.h>

#define NN 8192
#define FIN 256
#define FO 128
#define JCHUNK 1024             // cols per ks-slice
#define NSTEP 16                // 64-col steps
#define L2E 1.4426950408889634f
#define C2  0.28853900817779268f   // 0.2 * log2(e)

typedef __bf16 bf16x8 __attribute__((ext_vector_type(8)));
typedef __bf16 bf16x2 __attribute__((ext_vector_type(2)));
typedef float  f32x4  __attribute__((ext_vector_type(4)));
typedef unsigned long long u64;
typedef u64 u64x2 __attribute__((ext_vector_type(2)));

// ---------------------------------------------------------------------------
// Kernel 0: bit-pack adj (256 MB fp32 -> 8 MB bitmask).
// Rationale (rounds 1-2): k_attn reading adj directly achieves only ~1 TB/s
// because each wave-load touches 16 scattered rows (16 non-contiguous 64B
// lines/instr); two different stagings both landed ~160 us. The harness's own
// 1 GiB fill proves 6.76 TB/s on a contiguous pattern. So: stream adj with
// the PERFECT pattern here (wave reads contiguous 1 KB chunks of one row),
// ballot-pack to bits, and let k_attn consume 32x less adj data.
// Layout: row-major; per 256-col group g of row r, 4 u64 words at
// ab[r*128 + g*4 + k], where bit l of word k <-> adj[r][g*256 + l*4 + k].
// ---------------------------------------------------------------------------
__global__ __launch_bounds__(256) void k_pack(
    const float* __restrict__ adj, u64* __restrict__ ab)
{
  const int tid = threadIdx.x;
  const int w = tid >> 6, lane = tid & 63;
  const int row = blockIdx.x * 4 + w;                 // 2048 blocks -> 8192 rows
  const float4* src = (const float4*)(adj + (size_t)row * NN) + lane;
  u64* dst = ab + (size_t)row * 128;

  for (int g = 0; g < 32; g += 2) {
    float4 va = src[g * 64];            // wave: contiguous 1 KB
    float4 vb = src[g * 64 + 64];       // second load in flight before ballot wait
    u64 a0 = __ballot(va.x > 0.f);
    u64 a1 = __ballot(va.y > 0.f);
    u64 a2 = __ballot(va.z > 0.f);
    u64 a3 = __ballot(va.w > 0.f);
    if (lane < 4) {
      u64 m = lane == 0 ? a0 : lane == 1 ? a1 : lane == 2 ? a2 : a3;
      dst[g * 4 + lane] = m;
    }
    u64 b0 = __ballot(vb.x > 0.f);
    u64 b1 = __ballot(vb.y > 0.f);
    u64 b2 = __ballot(vb.z > 0.f);
    u64 b3 = __ballot(vb.w > 0.f);
    if (lane < 4) {
      u64 m = lane == 0 ? b0 : lane == 1 ? b1 : lane == 2 ? b2 : b3;
      dst[(g + 1) * 4 + lane] = m;
    }
  }
}

// ---------------------------------------------------------------------------
// Kernel 1: h = x@W (fp32 accum), write Bpack (bf16 MFMA-B-fragment layout),
//           f_src = h@a_src, f_dst = h@a_dst (fp32).
// Bpack element (kg, nt, lane=q*16+m, t) = h[j = kg*32+q*8+t][n = nt*16+m]
// ---------------------------------------------------------------------------
__global__ __launch_bounds__(256) void k_proj(
    const float* __restrict__ x, const float* __restrict__ W,
    const float* __restrict__ a_src, const float* __restrict__ a_dst,
    __bf16* __restrict__ Bp, float* __restrict__ f_src, float* __restrict__ f_dst)
{
  __shared__ float xs[16 * FIN];     // 16 KB x-tile
  __shared__ float fs[16], fd[16];
  const int tid = threadIdx.x;
  const int i0 = blockIdx.x * 16;

  const float4* xg = (const float4*)(x + (size_t)i0 * FIN);
  float4* xs4 = (float4*)xs;
  #pragma unroll
  for (int t = 0; t < 4; t++) xs4[tid + 256 * t] = xg[tid + 256 * t];
  if (tid < 16) { fs[tid] = 0.f; fd[tid] = 0.f; }
  __syncthreads();

  const int cq = tid & 31;    // column quad: cols c0..c0+3
  const int rg = tid >> 5;    // row group: rows r0, r0+1
  const int c0 = cq * 4;
  const int r0 = rg * 2;
  float acc0[4] = {0.f,0.f,0.f,0.f};
  float acc1[4] = {0.f,0.f,0.f,0.f};
  const float* xr0 = xs + r0 * FIN;
  const float* xr1 = xs + (r0 + 1) * FIN;

  for (int k = 0; k < FIN; k += 4) {
    float4 xa = *(const float4*)(xr0 + k);
    float4 xb = *(const float4*)(xr1 + k);
    #pragma unroll
    for (int kk = 0; kk < 4; kk++) {
      float4 wv = *(const float4*)(W + (size_t)(k + kk) * FO + c0);
      float xav = ((const float*)&xa)[kk];
      float xbv = ((const float*)&xb)[kk];
      acc0[0] += xav * wv.x; acc0[1] += xav * wv.y;
      acc0[2] += xav * wv.z; acc0[3] += xav * wv.w;
      acc1[0] += xbv * wv.x; acc1[1] += xbv * wv.y;
      acc1[2] += xbv * wv.z; acc1[3] += xbv * wv.w;
    }
  }

  float4 as = *(const float4*)(a_src + c0);
  float4 ad = *(const float4*)(a_dst + c0);
  float ps0 = acc0[0]*as.x + acc0[1]*as.y + acc0[2]*as.z + acc0[3]*as.w;
  float ps1 = acc1[0]*as.x + acc1[1]*as.y + acc1[2]*as.z + acc1[3]*as.w;
  float pd0 = acc0[0]*ad.x + acc0[1]*ad.y + acc0[2]*ad.z + acc0[3]*ad.w;
  float pd1 = acc1[0]*ad.x + acc1[1]*ad.y + acc1[2]*ad.z + acc1[3]*ad.w;
  atomicAdd(&fs[r0],     ps0);
  atomicAdd(&fs[r0 + 1], ps1);
  atomicAdd(&fd[r0],     pd0);
  atomicAdd(&fd[r0 + 1], pd1);

  const int j0 = i0 + r0;
  const int kg = j0 >> 5;
  const int q  = (j0 >> 3) & 3;
  const int t0 = j0 & 7;
  #pragma unroll
  for (int c = 0; c < 4; c++) {
    const int n = c0 + c;
    bf16x2 v;
    v[0] = (__bf16)acc0[c];
    v[1] = (__bf16)acc1[c];
    size_t idx = ((size_t)(kg * 8 + (n >> 4)) * 64 + q * 16 + (n & 15)) * 8 + t0;
    *(bf16x2*)(Bp + idx) = v;
  }
  __syncthreads();
  if (tid < 16) { f_src[i0 + tid] = fs[tid]; f_dst[i0 + tid] = fd[tid]; }
}

// ---------------------------------------------------------------------------
// Kernel 2: bitmask-driven P@H. adj arrives as 8 MB bitmask (L2/L3-resident):
// per wave-step only 2 broadcast u64 loads instead of 8 KB of floats.
// Wave owns 32 rows (two 16-row m-tiles) x 1024 cols. Per 64-col step:
// extract 8 bits/lane/m-tile from the ballot words, form
// p = bit ? max(F1_i*G1_j, F2_i*G2_j) : 0, pack bf16, MFMA against Bp.
// Bit address: col-local c in 256-group -> word k = c&3, bit l = c>>2;
// within a 64-col step ss of group: bit = ss*16 + kg*8 + q*2 (+1 for t>=4),
// word = t&3.
// ---------------------------------------------------------------------------
__global__ __launch_bounds__(256, 2) void k_attn(
    const u64* __restrict__ ab, const __bf16* __restrict__ Bp,
    const float* __restrict__ f_src, const float* __restrict__ f_dst,
    float* __restrict__ num, float* __restrict__ lsum)
{
  __shared__ float G1[JCHUNK];                         // 4 KB
  __shared__ float G2[JCHUNK];                         // 4 KB

  const int tid = threadIdx.x;
  const int rb = blockIdx.x >> 3;     // 0..63 (128 rows per block)
  const int ks = blockIdx.x & 7;
  const int i0 = rb * 128;
  const int jbase = ks * JCHUNK;

  const int w = tid >> 6;
  const int lane = tid & 63;
  const int m = lane & 15;
  const int q = lane >> 4;
  const int wbase = i0 + w * 32;

  float F1[2], F2[2];
  #pragma unroll
  for (int mt = 0; mt < 2; mt++) {
    float s = f_src[wbase + mt * 16 + m];
    F1[mt] = __builtin_amdgcn_exp2f(s * L2E);
    F2[mt] = __builtin_amdgcn_exp2f(s * C2);
  }

  #pragma unroll
  for (int t = 0; t < 4; t++) {
    int j = tid + t * 256;
    float d = f_dst[jbase + j];
    G1[j] = __builtin_amdgcn_exp2f(d * L2E);
    G2[j] = __builtin_amdgcn_exp2f(d * C2);
  }
  __syncthreads();   // G1/G2 visible; only barrier in the kernel

  f32x4 acc[2][8];
  #pragma unroll
  for (int mt = 0; mt < 2; mt++)
    #pragma unroll
    for (int nt = 0; nt < 8; nt++) acc[mt][nt] = (f32x4){0.f, 0.f, 0.f, 0.f};
  float psum[2] = {0.f, 0.f};

  // mask pointers: row stride 128 u64; this ks-slice = 4 groups = 16 u64
  const u64* abm0 = ab + (size_t)(wbase + m) * 128 + ks * 16;
  const u64* abm1 = abm0 + (size_t)16 * 128;
  const __bf16* bsrc_base = Bp + (size_t)ks * 32 * 4096 + lane * 8;

  for (int sg = 0; sg < 4; ++sg) {         // 4 steps (one 256-col group) per sg
    u64x2 Ma01 = *(const u64x2*)(abm0 + sg * 4);      // mt0: words k=0,1
    u64x2 Ma23 = *(const u64x2*)(abm0 + sg * 4 + 2);  // mt0: words k=2,3
    u64x2 Mb01 = *(const u64x2*)(abm1 + sg * 4);      // mt1
    u64x2 Mb23 = *(const u64x2*)(abm1 + sg * 4 + 2);

    #pragma unroll
    for (int ss = 0; ss < 4; ++ss) {
      const int step = sg * 4 + ss;
      #pragma unroll
      for (int kg = 0; kg < 2; kg++) {
        const int jj = step * 64 + kg * 32 + q * 8;
        float4 u0 = *(const float4*)(G1 + jj);
        float4 u1 = *(const float4*)(G1 + jj + 4);
        float4 v0 = *(const float4*)(G2 + jj);
        float4 v1 = *(const float4*)(G2 + jj + 4);
        const unsigned b = ss * 16 + kg * 8 + q * 2;   // bit pos (<=62)

        bf16x8 af[2];
        #pragma unroll
        for (int mt = 0; mt < 2; mt++) {
          const u64 M0 = mt ? Mb01[0] : Ma01[0];
          const u64 M1 = mt ? Mb01[1] : Ma01[1];
          const u64 M2 = mt ? Mb23[0] : Ma23[0];
          const u64 M3 = mt ? Mb23[1] : Ma23[1];
          const unsigned e0 = (unsigned)(M0 >> b);
          const unsigned e1 = (unsigned)(M1 >> b);
          const unsigned e2 = (unsigned)(M2 >> b);
          const unsigned e3 = (unsigned)(M3 >> b);
          const float f1 = F1[mt], f2 = F2[mt];
          float p0 = (e0 & 1u) ? fmaxf(f1 * u0.x, f2 * v0.x) : 0.f;
          float p1 = (e1 & 1u) ? fmaxf(f1 * u0.y, f2 * v0.y) : 0.f;
          float p2 = (e2 & 1u) ? fmaxf(f1 * u0.z, f2 * v0.z) : 0.f;
          float p3 = (e3 & 1u) ? fmaxf(f1 * u0.w, f2 * v0.w) : 0.f;
          float p4 = (e0 & 2u) ? fmaxf(f1 * u1.x, f2 * v1.x) : 0.f;
          float p5 = (e1 & 2u) ? fmaxf(f1 * u1.y, f2 * v1.y) : 0.f;
          float p6 = (e2 & 2u) ? fmaxf(f1 * u1.z, f2 * v1.z) : 0.f;
          float p7 = (e3 & 2u) ? fmaxf(f1 * u1.w, f2 * v1.w) : 0.f;
          psum[mt] += ((p0 + p1) + (p2 + p3)) + ((p4 + p5) + (p6 + p7));
          bf16x8 a;
          a[0] = (__bf16)p0; a[1] = (__bf16)p1; a[2] = (__bf16)p2;
          a[3] = (__bf16)p3; a[4] = (__bf16)p4; a[5] = (__bf16)p5;
          a[6] = (__bf16)p6; a[7] = (__bf16)p7;
          af[mt] = a;
        }

        const __bf16* bsrc = bsrc_base + (size_t)(step * 2 + kg) * 4096;
        #pragma unroll
        for (int nt = 0; nt < 8; nt++) {
          bf16x8 bfrag = *(const bf16x8*)(bsrc + nt * 512);
          acc[0][nt] = __builtin_amdgcn_mfma_f32_16x16x32_bf16(af[0], bfrag, acc[0][nt], 0, 0, 0);
          acc[1][nt] = __builtin_amdgcn_mfma_f32_16x16x32_bf16(af[1], bfrag, acc[1][nt], 0, 0, 0);
        }
      }
    }
  }

  // denominators: rows keyed by m live in lanes {m, m+16, m+32, m+48}
  #pragma unroll
  for (int mt = 0; mt < 2; mt++) {
    float p = psum[mt];
    p += __shfl_xor(p, 16);
    p += __shfl_xor(p, 32);
    if (lane < 16) atomicAdd(&lsum[wbase + mt * 16 + lane], p);
  }

  // numerators: C/D layout row=q*4+r, col=nt*16+m
  #pragma unroll
  for (int mt = 0; mt < 2; mt++) {
    const int rb0 = wbase + mt * 16 + q * 4;
    #pragma unroll
    for (int nt = 0; nt < 8; nt++) {
      #pragma unroll
      for (int r = 0; r < 4; r++) {
        atomicAdd(&num[(size_t)(rb0 + r) * FO + nt * 16 + m], acc[mt][nt][r]);
      }
    }
  }
}

// ---------------------------------------------------------------------------
// Kernel 3: out = num / l, vectorized float4.
// ---------------------------------------------------------------------------
__global__ __launch_bounds__(256) void k_div(
    const float* __restrict__ num, const float* __restrict__ lsum,
    float* __restrict__ out)
{
  int idx = blockIdx.x * 256 + threadIdx.x;        // float4 index
  float4 v = ((const float4*)num)[idx];
  float inv = 1.0f / lsum[idx >> 5];               // 32 float4 per row
  float4 o;
  o.x = v.x * inv; o.y = v.y * inv; o.z = v.z * inv; o.w = v.w * inv;
  ((float4*)out)[idx] = o;
}

extern "C" void kernel_launch(void* const* d_in, const int* in_sizes, int n_in,
                              void* d_out, int out_size, void* d_ws, size_t ws_size,
                              hipStream_t stream) {
  const float* x     = (const float*)d_in[0];
  const float* adj   = (const float*)d_in[1];
  const float* W     = (const float*)d_in[2];
  const float* a_src = (const float*)d_in[3];
  const float* a_dst = (const float*)d_in[4];
  float* out = (float*)d_out;

  char* ws = (char*)d_ws;
  __bf16* Bp   = (__bf16*)ws;                                  // 2 MB
  float* f_src = (float*)(ws + 2097152);                       // 32 KB
  float* f_dst = (float*)(ws + 2097152 + 32768);               // 32 KB
  float* num   = (float*)(ws + 2097152 + 65536);               // 4 MB
  float* lsum  = (float*)(ws + 2097152 + 65536 + 4194304);     // 32 KB
  u64*   ab    = (u64*)(ws + 8388608);                         // 8 MB bitmask

  hipMemsetAsync(num, 0, 4194304 + 32768, stream);             // zero num + lsum
  hipLaunchKernelGGL(k_pack, dim3(2048), dim3(256), 0, stream, adj, ab);
  hipLaunchKernelGGL(k_proj, dim3(512), dim3(256), 0, stream,
                     x, W, a_src, a_dst, Bp, f_src, f_dst);
  hipLaunchKernelGGL(k_attn, dim3(512), dim3(256), 0, stream,
                     ab, Bp, f_src, f_dst, num, lsum);
  hipLaunchKernelGGL(k_div, dim3(1024), dim3(256), 0, stream,
                     num, lsum, out);
}

// Round 5
// 471.748 us; speedup vs baseline: 1.0445x; 1.0445x over previous
//
#include <hip/hip_runtime.h>
#include <hip/hip_bf16.h>

#define NN 8192
#define FIN 256
#define FO 128
#define JCHUNK 1024             // cols per ks-slice
#define NSTEP 16                // 64-col steps
#define L2E 1.4426950408889634f
#define C2  0.28853900817779268f   // 0.2 * log2(e)

typedef __bf16 bf16x8 __attribute__((ext_vector_type(8)));
typedef __bf16 bf16x2 __attribute__((ext_vector_type(2)));
typedef float  f32x4  __attribute__((ext_vector_type(4)));
typedef unsigned long long u64;
typedef u64 u64x2 __attribute__((ext_vector_type(2)));

// ---------------------------------------------------------------------------
// Kernel 0: bit-pack adj (256 MB fp32 -> 8 MB bitmask).
// Streams adj with the ideal contiguous pattern (wave reads 1 KB chunks of
// one row), ballot-packs to bits. Measured ~51 us (round2->3 delta).
// Layout: per 256-col group g of row r, 4 u64 words at ab[r*128 + g*4 + k],
// bit l of word k <-> adj[r][g*256 + l*4 + k].
// ---------------------------------------------------------------------------
__global__ __launch_bounds__(256) void k_pack(
    const float* __restrict__ adj, u64* __restrict__ ab)
{
  const int tid = threadIdx.x;
  const int w = tid >> 6, lane = tid & 63;
  const int row = blockIdx.x * 4 + w;                 // 2048 blocks -> 8192 rows
  const float4* src = (const float4*)(adj + (size_t)row * NN) + lane;
  u64* dst = ab + (size_t)row * 128;

  for (int g = 0; g < 32; g += 2) {
    float4 va = src[g * 64];            // wave: contiguous 1 KB
    float4 vb = src[g * 64 + 64];       // second load in flight before ballot wait
    u64 a0 = __ballot(va.x > 0.f);
    u64 a1 = __ballot(va.y > 0.f);
    u64 a2 = __ballot(va.z > 0.f);
    u64 a3 = __ballot(va.w > 0.f);
    if (lane < 4) {
      u64 m = lane == 0 ? a0 : lane == 1 ? a1 : lane == 2 ? a2 : a3;
      dst[g * 4 + lane] = m;
    }
    u64 b0 = __ballot(vb.x > 0.f);
    u64 b1 = __ballot(vb.y > 0.f);
    u64 b2 = __ballot(vb.z > 0.f);
    u64 b3 = __ballot(vb.w > 0.f);
    if (lane < 4) {
      u64 m = lane == 0 ? b0 : lane == 1 ? b1 : lane == 2 ? b2 : b3;
      dst[(g + 1) * 4 + lane] = m;
    }
  }
}

// ---------------------------------------------------------------------------
// Kernel 1: h = x@W (fp32 accum), write Bpack (bf16 MFMA-B-fragment layout),
//           f_src = h@a_src, f_dst = h@a_dst (fp32).
// Bpack element (kg, nt, lane=q*16+m, t) = h[j = kg*32+q*8+t][n = nt*16+m]
// ---------------------------------------------------------------------------
__global__ __launch_bounds__(256) void k_proj(
    const float* __restrict__ x, const float* __restrict__ W,
    const float* __restrict__ a_src, const float* __restrict__ a_dst,
    __bf16* __restrict__ Bp, float* __restrict__ f_src, float* __restrict__ f_dst)
{
  __shared__ float xs[16 * FIN];     // 16 KB x-tile
  __shared__ float fs[16], fd[16];
  const int tid = threadIdx.x;
  const int i0 = blockIdx.x * 16;

  const float4* xg = (const float4*)(x + (size_t)i0 * FIN);
  float4* xs4 = (float4*)xs;
  #pragma unroll
  for (int t = 0; t < 4; t++) xs4[tid + 256 * t] = xg[tid + 256 * t];
  if (tid < 16) { fs[tid] = 0.f; fd[tid] = 0.f; }
  __syncthreads();

  const int cq = tid & 31;    // column quad: cols c0..c0+3
  const int rg = tid >> 5;    // row group: rows r0, r0+1
  const int c0 = cq * 4;
  const int r0 = rg * 2;
  float acc0[4] = {0.f,0.f,0.f,0.f};
  float acc1[4] = {0.f,0.f,0.f,0.f};
  const float* xr0 = xs + r0 * FIN;
  const float* xr1 = xs + (r0 + 1) * FIN;

  for (int k = 0; k < FIN; k += 4) {
    float4 xa = *(const float4*)(xr0 + k);
    float4 xb = *(const float4*)(xr1 + k);
    #pragma unroll
    for (int kk = 0; kk < 4; kk++) {
      float4 wv = *(const float4*)(W + (size_t)(k + kk) * FO + c0);
      float xav = ((const float*)&xa)[kk];
      float xbv = ((const float*)&xb)[kk];
      acc0[0] += xav * wv.x; acc0[1] += xav * wv.y;
      acc0[2] += xav * wv.z; acc0[3] += xav * wv.w;
      acc1[0] += xbv * wv.x; acc1[1] += xbv * wv.y;
      acc1[2] += xbv * wv.z; acc1[3] += xbv * wv.w;
    }
  }

  float4 as = *(const float4*)(a_src + c0);
  float4 ad = *(const float4*)(a_dst + c0);
  float ps0 = acc0[0]*as.x + acc0[1]*as.y + acc0[2]*as.z + acc0[3]*as.w;
  float ps1 = acc1[0]*as.x + acc1[1]*as.y + acc1[2]*as.z + acc1[3]*as.w;
  float pd0 = acc0[0]*ad.x + acc0[1]*ad.y + acc0[2]*ad.z + acc0[3]*ad.w;
  float pd1 = acc1[0]*ad.x + acc1[1]*ad.y + acc1[2]*ad.z + acc1[3]*ad.w;
  atomicAdd(&fs[r0],     ps0);
  atomicAdd(&fs[r0 + 1], ps1);
  atomicAdd(&fd[r0],     pd0);
  atomicAdd(&fd[r0 + 1], pd1);

  const int j0 = i0 + r0;
  const int kg = j0 >> 5;
  const int q  = (j0 >> 3) & 3;
  const int t0 = j0 & 7;
  #pragma unroll
  for (int c = 0; c < 4; c++) {
    const int n = c0 + c;
    bf16x2 v;
    v[0] = (__bf16)acc0[c];
    v[1] = (__bf16)acc1[c];
    size_t idx = ((size_t)(kg * 8 + (n >> 4)) * 64 + q * 16 + (n & 15)) * 8 + t0;
    *(bf16x2*)(Bp + idx) = v;
  }
  __syncthreads();
  if (tid < 16) { f_src[i0 + tid] = fs[tid]; f_dst[i0 + tid] = fd[tid]; }
}

// ---------------------------------------------------------------------------
// Kernel 2: bitmask-driven P@H, ATOMIC-FREE epilogue.
// Rounds 1-3: three different adj paths all gave k_attn ~155-169 us ->
// the invariant 8.4M contended global fp32 atomicAdds dominate, not adj
// traffic. Fix: each ks-slice writes its partial numerator to
// part[ks][row][col] with plain coalesced stores (each element owned by
// exactly one lane), partial denominators to lpart[ks][row]. k_div reduces.
// ---------------------------------------------------------------------------
__global__ __launch_bounds__(256, 2) void k_attn(
    const u64* __restrict__ ab, const __bf16* __restrict__ Bp,
    const float* __restrict__ f_src, const float* __restrict__ f_dst,
    float* __restrict__ part, float* __restrict__ lpart)
{
  __shared__ float G1[JCHUNK];                         // 4 KB
  __shared__ float G2[JCHUNK];                         // 4 KB

  const int tid = threadIdx.x;
  const int rb = blockIdx.x >> 3;     // 0..63 (128 rows per block)
  const int ks = blockIdx.x & 7;
  const int i0 = rb * 128;
  const int jbase = ks * JCHUNK;

  const int w = tid >> 6;
  const int lane = tid & 63;
  const int m = lane & 15;
  const int q = lane >> 4;
  const int wbase = i0 + w * 32;

  float F1[2], F2[2];
  #pragma unroll
  for (int mt = 0; mt < 2; mt++) {
    float s = f_src[wbase + mt * 16 + m];
    F1[mt] = __builtin_amdgcn_exp2f(s * L2E);
    F2[mt] = __builtin_amdgcn_exp2f(s * C2);
  }

  #pragma unroll
  for (int t = 0; t < 4; t++) {
    int j = tid + t * 256;
    float d = f_dst[jbase + j];
    G1[j] = __builtin_amdgcn_exp2f(d * L2E);
    G2[j] = __builtin_amdgcn_exp2f(d * C2);
  }
  __syncthreads();   // G1/G2 visible; only barrier in the kernel

  f32x4 acc[2][8];
  #pragma unroll
  for (int mt = 0; mt < 2; mt++)
    #pragma unroll
    for (int nt = 0; nt < 8; nt++) acc[mt][nt] = (f32x4){0.f, 0.f, 0.f, 0.f};
  float psum[2] = {0.f, 0.f};

  // mask pointers: row stride 128 u64; this ks-slice = 4 groups = 16 u64
  const u64* abm0 = ab + (size_t)(wbase + m) * 128 + ks * 16;
  const u64* abm1 = abm0 + (size_t)16 * 128;
  const __bf16* bsrc_base = Bp + (size_t)ks * 32 * 4096 + lane * 8;

  for (int sg = 0; sg < 4; ++sg) {         // 4 steps (one 256-col group) per sg
    u64x2 Ma01 = *(const u64x2*)(abm0 + sg * 4);      // mt0: words k=0,1
    u64x2 Ma23 = *(const u64x2*)(abm0 + sg * 4 + 2);  // mt0: words k=2,3
    u64x2 Mb01 = *(const u64x2*)(abm1 + sg * 4);      // mt1
    u64x2 Mb23 = *(const u64x2*)(abm1 + sg * 4 + 2);

    #pragma unroll
    for (int ss = 0; ss < 4; ++ss) {
      const int step = sg * 4 + ss;
      #pragma unroll
      for (int kg = 0; kg < 2; kg++) {
        const int jj = step * 64 + kg * 32 + q * 8;
        float4 u0 = *(const float4*)(G1 + jj);
        float4 u1 = *(const float4*)(G1 + jj + 4);
        float4 v0 = *(const float4*)(G2 + jj);
        float4 v1 = *(const float4*)(G2 + jj + 4);
        const unsigned b = ss * 16 + kg * 8 + q * 2;   // bit pos (<=62)

        bf16x8 af[2];
        #pragma unroll
        for (int mt = 0; mt < 2; mt++) {
          const u64 M0 = mt ? Mb01[0] : Ma01[0];
          const u64 M1 = mt ? Mb01[1] : Ma01[1];
          const u64 M2 = mt ? Mb23[0] : Ma23[0];
          const u64 M3 = mt ? Mb23[1] : Ma23[1];
          const unsigned e0 = (unsigned)(M0 >> b);
          const unsigned e1 = (unsigned)(M1 >> b);
          const unsigned e2 = (unsigned)(M2 >> b);
          const unsigned e3 = (unsigned)(M3 >> b);
          const float f1 = F1[mt], f2 = F2[mt];
          float p0 = (e0 & 1u) ? fmaxf(f1 * u0.x, f2 * v0.x) : 0.f;
          float p1 = (e1 & 1u) ? fmaxf(f1 * u0.y, f2 * v0.y) : 0.f;
          float p2 = (e2 & 1u) ? fmaxf(f1 * u0.z, f2 * v0.z) : 0.f;
          float p3 = (e3 & 1u) ? fmaxf(f1 * u0.w, f2 * v0.w) : 0.f;
          float p4 = (e0 & 2u) ? fmaxf(f1 * u1.x, f2 * v1.x) : 0.f;
          float p5 = (e1 & 2u) ? fmaxf(f1 * u1.y, f2 * v1.y) : 0.f;
          float p6 = (e2 & 2u) ? fmaxf(f1 * u1.z, f2 * v1.z) : 0.f;
          float p7 = (e3 & 2u) ? fmaxf(f1 * u1.w, f2 * v1.w) : 0.f;
          psum[mt] += ((p0 + p1) + (p2 + p3)) + ((p4 + p5) + (p6 + p7));
          bf16x8 a;
          a[0] = (__bf16)p0; a[1] = (__bf16)p1; a[2] = (__bf16)p2;
          a[3] = (__bf16)p3; a[4] = (__bf16)p4; a[5] = (__bf16)p5;
          a[6] = (__bf16)p6; a[7] = (__bf16)p7;
          af[mt] = a;
        }

        const __bf16* bsrc = bsrc_base + (size_t)(step * 2 + kg) * 4096;
        #pragma unroll
        for (int nt = 0; nt < 8; nt++) {
          bf16x8 bfrag = *(const bf16x8*)(bsrc + nt * 512);
          acc[0][nt] = __builtin_amdgcn_mfma_f32_16x16x32_bf16(af[0], bfrag, acc[0][nt], 0, 0, 0);
          acc[1][nt] = __builtin_amdgcn_mfma_f32_16x16x32_bf16(af[1], bfrag, acc[1][nt], 0, 0, 0);
        }
      }
    }
  }

  // denominator partials: rows keyed by m live in lanes {m, m+16, m+32, m+48}
  float* ldst = lpart + (size_t)ks * NN;
  #pragma unroll
  for (int mt = 0; mt < 2; mt++) {
    float p = psum[mt];
    p += __shfl_xor(p, 16);
    p += __shfl_xor(p, 32);
    if (lane < 16) ldst[wbase + mt * 16 + lane] = p;
  }

  // numerator partials: C/D layout row=q*4+r, col=nt*16+m; plain stores —
  // each (ks,row,col) element owned by exactly one lane.
  float* pdst = part + (size_t)ks * NN * FO;
  #pragma unroll
  for (int mt = 0; mt < 2; mt++) {
    const int rb0 = wbase + mt * 16 + q * 4;
    #pragma unroll
    for (int nt = 0; nt < 8; nt++) {
      #pragma unroll
      for (int r = 0; r < 4; r++) {
        pdst[(size_t)(rb0 + r) * FO + nt * 16 + m] = acc[mt][nt][r];
      }
    }
  }
}

// ---------------------------------------------------------------------------
// Kernel 3: out = (sum_ks part) / (sum_ks lpart), vectorized float4.
// EXACTLY 262144 float4 outputs -> grid 1024 x 256 (round-4 crash was this
// grid at 2048: 524288 threads storing into a 4 MB out buffer = OOB write).
// ---------------------------------------------------------------------------
__global__ __launch_bounds__(256) void k_div(
    const float* __restrict__ part, const float* __restrict__ lpart,
    float* __restrict__ out)
{
  int idx = blockIdx.x * 256 + threadIdx.x;        // float4 index (262144 total)
  int row = idx >> 5;                              // 32 float4 per row
  float4 s = {0.f, 0.f, 0.f, 0.f};
  float l = 0.f;
  #pragma unroll
  for (int ks = 0; ks < 8; ks++) {
    float4 v = ((const float4*)(part + (size_t)ks * NN * FO))[idx];
    s.x += v.x; s.y += v.y; s.z += v.z; s.w += v.w;
    l += lpart[ks * NN + row];
  }
  float inv = 1.0f / l;
  float4 o;
  o.x = s.x * inv; o.y = s.y * inv; o.z = s.z * inv; o.w = s.w * inv;
  ((float4*)out)[idx] = o;
}

extern "C" void kernel_launch(void* const* d_in, const int* in_sizes, int n_in,
                              void* d_out, int out_size, void* d_ws, size_t ws_size,
                              hipStream_t stream) {
  const float* x     = (const float*)d_in[0];
  const float* adj   = (const float*)d_in[1];
  const float* W     = (const float*)d_in[2];
  const float* a_src = (const float*)d_in[3];
  const float* a_dst = (const float*)d_in[4];
  float* out = (float*)d_out;

  char* ws = (char*)d_ws;
  __bf16* Bp   = (__bf16*)ws;                      // 0 .. 2 MB
  float* f_src = (float*)(ws + 2097152);           // 32 KB
  float* f_dst = (float*)(ws + 2097152 + 32768);   // 32 KB
  u64*   ab    = (u64*)(ws + 4194304);             // 4 MB .. 12 MB bitmask
  float* part  = (float*)(ws + 16777216);          // 16 MB .. 48 MB partials
  float* lpart = (float*)(ws + 50331648);          // 256 KB denom partials

  // No memset needed: part/lpart/out are fully written.
  hipLaunchKernelGGL(k_pack, dim3(2048), dim3(256), 0, stream, adj, ab);
  hipLaunchKernelGGL(k_proj, dim3(512), dim3(256), 0, stream,
                     x, W, a_src, a_dst, Bp, f_src, f_dst);
  hipLaunchKernelGGL(k_attn, dim3(512), dim3(256), 0, stream,
                     ab, Bp, f_src, f_dst, part, lpart);
  hipLaunchKernelGGL(k_div, dim3(1024), dim3(256), 0, stream,
                     part, lpart, out);
}

// Round 6
// 468.243 us; speedup vs baseline: 1.0523x; 1.0075x over previous
//
#include <hip/hip_runtime.h>
#include <hip/hip_bf16.h>

#define NN 8192
#define FIN 256
#define FO 128
#define KSPLIT 16
#define JCHUNK 512              // cols per ks-slice (NN/KSPLIT)
#define NSTEP 8                 // 64-col steps (JCHUNK/64)
#define SGN 2                   // 256-col groups (JCHUNK/256)
#define MSTRIDE 10              // u64 per mask row (8 + 2 pad: 80B = 20 banks -> 2-way only)
#define L2E 1.4426950408889634f
#define C2  0.28853900817779268f   // 0.2 * log2(e)

typedef __bf16 bf16x8 __attribute__((ext_vector_type(8)));
typedef __bf16 bf16x2 __attribute__((ext_vector_type(2)));
typedef float  f32x4  __attribute__((ext_vector_type(4)));
typedef unsigned long long u64;
typedef u64 u64x2 __attribute__((ext_vector_type(2)));

// ---------------------------------------------------------------------------
// Kernel 1: h = x@W (fp32 accum), write Bpack (bf16 MFMA-B-fragment layout),
//           f_src = h@a_src, f_dst = h@a_dst (fp32).  (unchanged)
// Bpack element (kg, nt, lane=q*16+m, t) = h[j = kg*32+q*8+t][n = nt*16+m]
// ---------------------------------------------------------------------------
__global__ __launch_bounds__(256) void k_proj(
    const float* __restrict__ x, const float* __restrict__ W,
    const float* __restrict__ a_src, const float* __restrict__ a_dst,
    __bf16* __restrict__ Bp, float* __restrict__ f_src, float* __restrict__ f_dst)
{
  __shared__ float xs[16 * FIN];     // 16 KB x-tile
  __shared__ float fs[16], fd[16];
  const int tid = threadIdx.x;
  const int i0 = blockIdx.x * 16;

  const float4* xg = (const float4*)(x + (size_t)i0 * FIN);
  float4* xs4 = (float4*)xs;
  #pragma unroll
  for (int t = 0; t < 4; t++) xs4[tid + 256 * t] = xg[tid + 256 * t];
  if (tid < 16) { fs[tid] = 0.f; fd[tid] = 0.f; }
  __syncthreads();

  const int cq = tid & 31;    // column quad: cols c0..c0+3
  const int rg = tid >> 5;    // row group: rows r0, r0+1
  const int c0 = cq * 4;
  const int r0 = rg * 2;
  float acc0[4] = {0.f,0.f,0.f,0.f};
  float acc1[4] = {0.f,0.f,0.f,0.f};
  const float* xr0 = xs + r0 * FIN;
  const float* xr1 = xs + (r0 + 1) * FIN;

  for (int k = 0; k < FIN; k += 4) {
    float4 xa = *(const float4*)(xr0 + k);
    float4 xb = *(const float4*)(xr1 + k);
    #pragma unroll
    for (int kk = 0; kk < 4; kk++) {
      float4 wv = *(const float4*)(W + (size_t)(k + kk) * FO + c0);
      float xav = ((const float*)&xa)[kk];
      float xbv = ((const float*)&xb)[kk];
      acc0[0] += xav * wv.x; acc0[1] += xav * wv.y;
      acc0[2] += xav * wv.z; acc0[3] += xav * wv.w;
      acc1[0] += xbv * wv.x; acc1[1] += xbv * wv.y;
      acc1[2] += xbv * wv.z; acc1[3] += xbv * wv.w;
    }
  }

  float4 as = *(const float4*)(a_src + c0);
  float4 ad = *(const float4*)(a_dst + c0);
  float ps0 = acc0[0]*as.x + acc0[1]*as.y + acc0[2]*as.z + acc0[3]*as.w;
  float ps1 = acc1[0]*as.x + acc1[1]*as.y + acc1[2]*as.z + acc1[3]*as.w;
  float pd0 = acc0[0]*ad.x + acc0[1]*ad.y + acc0[2]*ad.z + acc0[3]*ad.w;
  float pd1 = acc1[0]*ad.x + acc1[1]*ad.y + acc1[2]*ad.z + acc1[3]*ad.w;
  atomicAdd(&fs[r0],     ps0);
  atomicAdd(&fs[r0 + 1], ps1);
  atomicAdd(&fd[r0],     pd0);
  atomicAdd(&fd[r0 + 1], pd1);

  const int j0 = i0 + r0;
  const int kg = j0 >> 5;
  const int q  = (j0 >> 3) & 3;
  const int t0 = j0 & 7;
  #pragma unroll
  for (int c = 0; c < 4; c++) {
    const int n = c0 + c;
    bf16x2 v;
    v[0] = (__bf16)acc0[c];
    v[1] = (__bf16)acc1[c];
    size_t idx = ((size_t)(kg * 8 + (n >> 4)) * 64 + q * 16 + (n & 15)) * 8 + t0;
    *(bf16x2*)(Bp + idx) = v;
  }
  __syncthreads();
  if (tid < 16) { f_src[i0 + tid] = fs[tid]; f_dst[i0 + tid] = fd[tid]; }
}

// ---------------------------------------------------------------------------
// Kernel 2: FUSED pack+consume P@H, atomic-free.
// Round-5 post-mortem: k_attn = 132 us vs ~25 us static model -> ~80% stall,
// and the grid (512 blocks = 2 blocks/CU, Occupancy 21.7%) exposes all
// Bp/mask L2 latency. Also k_pack's 8 MB bitmask round-trip (51 us) serves
// only this kernel, and each block's mask tile is its own disjoint adj
// region. Fix: (1) each wave ballot-packs its OWN 32 rows x 512 cols of adj
// (contiguous 1 KB wave-loads, the proven-fast pattern) into a 10 KB LDS
// bitmask - no extra barrier needed (per-wave LDS ordering); (2) KSPLIT=16
// -> 1024 blocks = 4 blocks/CU, doubling latency hiding; pack (memory) of
// one wave/block overlaps consume (MFMA/VALU) of others.
// Mask layout: msk[r][sg*4+k], bit l of word k <-> col sg*256 + l*4 + k.
// ---------------------------------------------------------------------------
__global__ __launch_bounds__(256) void k_attn(
    const float* __restrict__ adj, const __bf16* __restrict__ Bp,
    const float* __restrict__ f_src, const float* __restrict__ f_dst,
    float* __restrict__ part, float* __restrict__ lpart)
{
  __shared__ float G1[JCHUNK];                        // 2 KB
  __shared__ float G2[JCHUNK];                        // 2 KB
  __shared__ __align__(16) u64 msk[128][MSTRIDE];     // 10 KB

  const int tid = threadIdx.x;
  const int rb = blockIdx.x >> 4;     // 0..63 (128 rows per block)
  const int ks = blockIdx.x & 15;     // 0..15
  const int i0 = rb * 128;
  const int jbase = ks * JCHUNK;

  const int w = tid >> 6;
  const int lane = tid & 63;
  const int m = lane & 15;
  const int q = lane >> 4;
  const int wbase = i0 + w * 32;

  float F1[2], F2[2];
  #pragma unroll
  for (int mt = 0; mt < 2; mt++) {
    float s = f_src[wbase + mt * 16 + m];
    F1[mt] = __builtin_amdgcn_exp2f(s * L2E);
    F2[mt] = __builtin_amdgcn_exp2f(s * C2);
  }

  #pragma unroll
  for (int t = 0; t < 2; t++) {
    int j = tid + t * 256;
    float d = f_dst[jbase + j];
    G1[j] = __builtin_amdgcn_exp2f(d * L2E);
    G2[j] = __builtin_amdgcn_exp2f(d * C2);
  }
  __syncthreads();   // G1/G2 visible to all waves (msk is per-wave, no barrier)

  // ---- pack phase: wave w streams its rows w*32..w*32+31, contiguous 1 KB
  // wave-loads (64 lanes x float4), ballots into the LDS bitmask.
  const float* abase = adj + (size_t)wbase * NN + jbase + lane * 4;
  #pragma unroll 2
  for (int rr = 0; rr < 32; ++rr) {
    const float* rp = abase + (size_t)rr * NN;
    float4 c0 = *(const float4*)rp;           // cols jbase+0..255
    float4 c1 = *(const float4*)(rp + 256);   // cols jbase+256..511
    u64 w00 = __ballot(c0.x > 0.f);
    u64 w01 = __ballot(c0.y > 0.f);
    u64 w02 = __ballot(c0.z > 0.f);
    u64 w03 = __ballot(c0.w > 0.f);
    u64 w10 = __ballot(c1.x > 0.f);
    u64 w11 = __ballot(c1.y > 0.f);
    u64 w12 = __ballot(c1.z > 0.f);
    u64 w13 = __ballot(c1.w > 0.f);
    if (lane < 8) {
      u64 v = lane == 0 ? w00 : lane == 1 ? w01 : lane == 2 ? w02 :
              lane == 3 ? w03 : lane == 4 ? w10 : lane == 5 ? w11 :
              lane == 6 ? w12 : w13;
      msk[w * 32 + rr][lane] = v;
    }
  }

  // ---- consume phase
  f32x4 acc[2][8];
  #pragma unroll
  for (int mt = 0; mt < 2; mt++)
    #pragma unroll
    for (int nt = 0; nt < 8; nt++) acc[mt][nt] = (f32x4){0.f, 0.f, 0.f, 0.f};
  float psum[2] = {0.f, 0.f};

  const int r0l = w * 32 + m;
  const __bf16* bsrc_base = Bp + (size_t)ks * 16 * 4096 + lane * 8;

  for (int sg = 0; sg < SGN; ++sg) {        // one 256-col group per sg
    u64x2 Ma01 = *(const u64x2*)&msk[r0l][sg * 4];
    u64x2 Ma23 = *(const u64x2*)&msk[r0l][sg * 4 + 2];
    u64x2 Mb01 = *(const u64x2*)&msk[r0l + 16][sg * 4];
    u64x2 Mb23 = *(const u64x2*)&msk[r0l + 16][sg * 4 + 2];

    #pragma unroll
    for (int ss = 0; ss < 4; ++ss) {
      const int step = sg * 4 + ss;
      #pragma unroll
      for (int kg = 0; kg < 2; kg++) {
        const int jj = step * 64 + kg * 32 + q * 8;
        float4 u0 = *(const float4*)(G1 + jj);
        float4 u1 = *(const float4*)(G1 + jj + 4);
        float4 v0 = *(const float4*)(G2 + jj);
        float4 v1 = *(const float4*)(G2 + jj + 4);
        const unsigned b = ss * 16 + kg * 8 + q * 2;   // bit pos (<=62)

        bf16x8 af[2];
        #pragma unroll
        for (int mt = 0; mt < 2; mt++) {
          const u64 M0 = mt ? Mb01[0] : Ma01[0];
          const u64 M1 = mt ? Mb01[1] : Ma01[1];
          const u64 M2 = mt ? Mb23[0] : Ma23[0];
          const u64 M3 = mt ? Mb23[1] : Ma23[1];
          const unsigned e0 = (unsigned)(M0 >> b);
          const unsigned e1 = (unsigned)(M1 >> b);
          const unsigned e2 = (unsigned)(M2 >> b);
          const unsigned e3 = (unsigned)(M3 >> b);
          const float f1 = F1[mt], f2 = F2[mt];
          float p0 = (e0 & 1u) ? fmaxf(f1 * u0.x, f2 * v0.x) : 0.f;
          float p1 = (e1 & 1u) ? fmaxf(f1 * u0.y, f2 * v0.y) : 0.f;
          float p2 = (e2 & 1u) ? fmaxf(f1 * u0.z, f2 * v0.z) : 0.f;
          float p3 = (e3 & 1u) ? fmaxf(f1 * u0.w, f2 * v0.w) : 0.f;
          float p4 = (e0 & 2u) ? fmaxf(f1 * u1.x, f2 * v1.x) : 0.f;
          float p5 = (e1 & 2u) ? fmaxf(f1 * u1.y, f2 * v1.y) : 0.f;
          float p6 = (e2 & 2u) ? fmaxf(f1 * u1.z, f2 * v1.z) : 0.f;
          float p7 = (e3 & 2u) ? fmaxf(f1 * u1.w, f2 * v1.w) : 0.f;
          psum[mt] += ((p0 + p1) + (p2 + p3)) + ((p4 + p5) + (p6 + p7));
          bf16x8 a;
          a[0] = (__bf16)p0; a[1] = (__bf16)p1; a[2] = (__bf16)p2;
          a[3] = (__bf16)p3; a[4] = (__bf16)p4; a[5] = (__bf16)p5;
          a[6] = (__bf16)p6; a[7] = (__bf16)p7;
          af[mt] = a;
        }

        const __bf16* bsrc = bsrc_base + (size_t)(step * 2 + kg) * 4096;
        #pragma unroll
        for (int nt = 0; nt < 8; nt++) {
          bf16x8 bfrag = *(const bf16x8*)(bsrc + nt * 512);
          acc[0][nt] = __builtin_amdgcn_mfma_f32_16x16x32_bf16(af[0], bfrag, acc[0][nt], 0, 0, 0);
          acc[1][nt] = __builtin_amdgcn_mfma_f32_16x16x32_bf16(af[1], bfrag, acc[1][nt], 0, 0, 0);
        }
      }
    }
  }

  // denominator partials: rows keyed by m live in lanes {m, m+16, m+32, m+48}
  float* ldst = lpart + (size_t)ks * NN;
  #pragma unroll
  for (int mt = 0; mt < 2; mt++) {
    float p = psum[mt];
    p += __shfl_xor(p, 16);
    p += __shfl_xor(p, 32);
    if (lane < 16) ldst[wbase + mt * 16 + lane] = p;
  }

  // numerator partials: C/D layout row=q*4+r, col=nt*16+m; plain stores —
  // each (ks,row,col) element owned by exactly one lane.
  float* pdst = part + (size_t)ks * NN * FO;
  #pragma unroll
  for (int mt = 0; mt < 2; mt++) {
    const int rb0 = wbase + mt * 16 + q * 4;
    #pragma unroll
    for (int nt = 0; nt < 8; nt++) {
      #pragma unroll
      for (int r = 0; r < 4; r++) {
        pdst[(size_t)(rb0 + r) * FO + nt * 16 + m] = acc[mt][nt][r];
      }
    }
  }
}

// ---------------------------------------------------------------------------
// Kernel 3: out = (sum_ks part) / (sum_ks lpart), vectorized float4.
// EXACTLY 262144 float4 outputs -> grid 1024 x 256.
// ---------------------------------------------------------------------------
__global__ __launch_bounds__(256) void k_div(
    const float* __restrict__ part, const float* __restrict__ lpart,
    float* __restrict__ out)
{
  int idx = blockIdx.x * 256 + threadIdx.x;        // float4 index (262144 total)
  int row = idx >> 5;                              // 32 float4 per row
  float4 s = {0.f, 0.f, 0.f, 0.f};
  float l = 0.f;
  #pragma unroll
  for (int ks = 0; ks < KSPLIT; ks++) {
    float4 v = ((const float4*)(part + (size_t)ks * NN * FO))[idx];
    s.x += v.x; s.y += v.y; s.z += v.z; s.w += v.w;
    l += lpart[ks * NN + row];
  }
  float inv = 1.0f / l;
  float4 o;
  o.x = s.x * inv; o.y = s.y * inv; o.z = s.z * inv; o.w = s.w * inv;
  ((float4*)out)[idx] = o;
}

extern "C" void kernel_launch(void* const* d_in, const int* in_sizes, int n_in,
                              void* d_out, int out_size, void* d_ws, size_t ws_size,
                              hipStream_t stream) {
  const float* x     = (const float*)d_in[0];
  const float* adj   = (const float*)d_in[1];
  const float* W     = (const float*)d_in[2];
  const float* a_src = (const float*)d_in[3];
  const float* a_dst = (const float*)d_in[4];
  float* out = (float*)d_out;

  char* ws = (char*)d_ws;
  __bf16* Bp   = (__bf16*)ws;                      // 0 .. 2 MB
  float* f_src = (float*)(ws + 2097152);           // 32 KB
  float* f_dst = (float*)(ws + 2097152 + 32768);   // 32 KB
  float* part  = (float*)(ws + 16777216);          // 16 MB .. 80 MB (16 x 4 MB)
  float* lpart = (float*)(ws + 83886080);          // 80 MB .. +512 KB

  // No memset needed: part/lpart/out are fully written.
  hipLaunchKernelGGL(k_proj, dim3(512), dim3(256), 0, stream,
                     x, W, a_src, a_dst, Bp, f_src, f_dst);
  hipLaunchKernelGGL(k_attn, dim3(1024), dim3(256), 0, stream,
                     adj, Bp, f_src, f_dst, part, lpart);
  hipLaunchKernelGGL(k_div, dim3(1024), dim3(256), 0, stream,
                     part, lpart, out);
}

// Round 7
// 447.424 us; speedup vs baseline: 1.1013x; 1.0465x over previous
//
#include <hip/hip_runtime.h>
#include <hip/hip_bf16.h>

#define NN 8192
#define FIN 256
#define FO 128
#define KSPLIT 16
#define JCHUNK 512              // cols per ks-slice (NN/KSPLIT)
#define NSTEP 8                 // 64-col steps (JCHUNK/64)
#define SGN 2                   // 256-col groups (JCHUNK/256)
#define MSTRIDE 10              // u64 per mask row (8 + 2 pad)
#define L2E 1.4426950408889634f
#define C2  0.28853900817779268f   // 0.2 * log2(e)

typedef __bf16 bf16x8 __attribute__((ext_vector_type(8)));
typedef __bf16 bf16x2 __attribute__((ext_vector_type(2)));
typedef float  f32x4  __attribute__((ext_vector_type(4)));
typedef unsigned long long u64;
typedef u64 u64x2 __attribute__((ext_vector_type(2)));

// ---------------------------------------------------------------------------
// Kernel 1: h = x@W (fp32 accum), write Bpack (bf16 MFMA-B-fragment layout),
//           f_src = h@a_src, f_dst = h@a_dst (fp32).  (unchanged)
// Bpack element (kg, nt, lane=q*16+m, t) = h[j = kg*32+q*8+t][n = nt*16+m]
// ---------------------------------------------------------------------------
__global__ __launch_bounds__(256) void k_proj(
    const float* __restrict__ x, const float* __restrict__ W,
    const float* __restrict__ a_src, const float* __restrict__ a_dst,
    __bf16* __restrict__ Bp, float* __restrict__ f_src, float* __restrict__ f_dst)
{
  __shared__ float xs[16 * FIN];     // 16 KB x-tile
  __shared__ float fs[16], fd[16];
  const int tid = threadIdx.x;
  const int i0 = blockIdx.x * 16;

  const float4* xg = (const float4*)(x + (size_t)i0 * FIN);
  float4* xs4 = (float4*)xs;
  #pragma unroll
  for (int t = 0; t < 4; t++) xs4[tid + 256 * t] = xg[tid + 256 * t];
  if (tid < 16) { fs[tid] = 0.f; fd[tid] = 0.f; }
  __syncthreads();

  const int cq = tid & 31;    // column quad: cols c0..c0+3
  const int rg = tid >> 5;    // row group: rows r0, r0+1
  const int c0 = cq * 4;
  const int r0 = rg * 2;
  float acc0[4] = {0.f,0.f,0.f,0.f};
  float acc1[4] = {0.f,0.f,0.f,0.f};
  const float* xr0 = xs + r0 * FIN;
  const float* xr1 = xs + (r0 + 1) * FIN;

  for (int k = 0; k < FIN; k += 4) {
    float4 xa = *(const float4*)(xr0 + k);
    float4 xb = *(const float4*)(xr1 + k);
    #pragma unroll
    for (int kk = 0; kk < 4; kk++) {
      float4 wv = *(const float4*)(W + (size_t)(k + kk) * FO + c0);
      float xav = ((const float*)&xa)[kk];
      float xbv = ((const float*)&xb)[kk];
      acc0[0] += xav * wv.x; acc0[1] += xav * wv.y;
      acc0[2] += xav * wv.z; acc0[3] += xav * wv.w;
      acc1[0] += xbv * wv.x; acc1[1] += xbv * wv.y;
      acc1[2] += xbv * wv.z; acc1[3] += xbv * wv.w;
    }
  }

  float4 as = *(const float4*)(a_src + c0);
  float4 ad = *(const float4*)(a_dst + c0);
  float ps0 = acc0[0]*as.x + acc0[1]*as.y + acc0[2]*as.z + acc0[3]*as.w;
  float ps1 = acc1[0]*as.x + acc1[1]*as.y + acc1[2]*as.z + acc1[3]*as.w;
  float pd0 = acc0[0]*ad.x + acc0[1]*ad.y + acc0[2]*ad.z + acc0[3]*ad.w;
  float pd1 = acc1[0]*ad.x + acc1[1]*ad.y + acc1[2]*ad.z + acc1[3]*ad.w;
  atomicAdd(&fs[r0],     ps0);
  atomicAdd(&fs[r0 + 1], ps1);
  atomicAdd(&fd[r0],     pd0);
  atomicAdd(&fd[r0 + 1], pd1);

  const int j0 = i0 + r0;
  const int kg = j0 >> 5;
  const int q  = (j0 >> 3) & 3;
  const int t0 = j0 & 7;
  #pragma unroll
  for (int c = 0; c < 4; c++) {
    const int n = c0 + c;
    bf16x2 v;
    v[0] = (__bf16)acc0[c];
    v[1] = (__bf16)acc1[c];
    size_t idx = ((size_t)(kg * 8 + (n >> 4)) * 64 + q * 16 + (n & 15)) * 8 + t0;
    *(bf16x2*)(Bp + idx) = v;
  }
  __syncthreads();
  if (tid < 16) { f_src[i0 + tid] = fs[tid]; f_dst[i0 + tid] = fd[tid]; }
}

// ---------------------------------------------------------------------------
// Kernel 2: fused pack+consume P@H, REGISTER-DIET version.
// Round-6 diagnosis: Occupancy stuck at 22% in r5 AND r6 = 2 blocks/CU.
// gfx950 unified VGPR/AGPR file: reported 88-96 VGPR + 64 acc AGPRs
// (acc[2][8]) = ~152-160 regs/wave -> >128 -> 2 waves/SIMD. All latency
// exposed -> the stubborn ~160 us. Fix: split FO across wave pairs.
// Block = 64 rows x JCHUNK cols, 4 waves: wave w -> row-pair p=w>>1
// (rows p*32..p*32+31), nt-half nh=w&1 (output cols nh*64..nh*64+63).
// acc[2][4] = 32 acc regs; __launch_bounds__(256,4) caps total at 128
// -> 4 waves/SIMD. Each wave packs 16 rows (block covers 64 once),
// masks shared via LDS (one barrier). adj+Bp traffic totals unchanged;
// only the cheap p-compute VALU is duplicated across the nt-split.
// Grid 2048 blocks = 8/CU queued, ~4 resident.
// ---------------------------------------------------------------------------
__global__ __launch_bounds__(256, 4) void k_attn(
    const float* __restrict__ adj, const __bf16* __restrict__ Bp,
    const float* __restrict__ f_src, const float* __restrict__ f_dst,
    float* __restrict__ part, float* __restrict__ lpart)
{
  __shared__ float G1[JCHUNK];                        // 2 KB
  __shared__ float G2[JCHUNK];                        // 2 KB
  __shared__ __align__(16) u64 msk[64][MSTRIDE];      // 5 KB

  const int tid = threadIdx.x;
  const int rb = blockIdx.x >> 4;     // 0..127 (64 rows per block)
  const int ks = blockIdx.x & 15;     // 0..15
  const int i0 = rb * 64;
  const int jbase = ks * JCHUNK;

  const int w = tid >> 6;
  const int lane = tid & 63;
  const int m = lane & 15;
  const int q = lane >> 4;
  const int p  = w >> 1;              // row-pair: rows p*32..p*32+31
  const int nh = w & 1;               // nt-half: nt = nh*4 .. nh*4+3
  const int wbase = i0 + p * 32;

  float F1[2], F2[2];
  #pragma unroll
  for (int mt = 0; mt < 2; mt++) {
    float s = f_src[wbase + mt * 16 + m];
    F1[mt] = __builtin_amdgcn_exp2f(s * L2E);
    F2[mt] = __builtin_amdgcn_exp2f(s * C2);
  }

  #pragma unroll
  for (int t = 0; t < 2; t++) {
    int j = tid + t * 256;
    float d = f_dst[jbase + j];
    G1[j] = __builtin_amdgcn_exp2f(d * L2E);
    G2[j] = __builtin_amdgcn_exp2f(d * C2);
  }

  // ---- pack phase: wave w packs rows p*32 + nh*16 .. +15 (16 rows),
  // contiguous 1 KB wave-loads (64 lanes x float4), ballots to LDS bitmask.
  {
    const int prow = p * 32 + nh * 16;               // block-local first row
    const float* abase = adj + (size_t)(i0 + prow) * NN + jbase + lane * 4;
    #pragma unroll 2
    for (int rr = 0; rr < 16; ++rr) {
      const float* rp = abase + (size_t)rr * NN;
      float4 c0 = *(const float4*)rp;           // cols jbase+0..255
      float4 c1 = *(const float4*)(rp + 256);   // cols jbase+256..511
      u64 w00 = __ballot(c0.x > 0.f);
      u64 w01 = __ballot(c0.y > 0.f);
      u64 w02 = __ballot(c0.z > 0.f);
      u64 w03 = __ballot(c0.w > 0.f);
      u64 w10 = __ballot(c1.x > 0.f);
      u64 w11 = __ballot(c1.y > 0.f);
      u64 w12 = __ballot(c1.z > 0.f);
      u64 w13 = __ballot(c1.w > 0.f);
      if (lane < 8) {
        u64 v = lane == 0 ? w00 : lane == 1 ? w01 : lane == 2 ? w02 :
                lane == 3 ? w03 : lane == 4 ? w10 : lane == 5 ? w11 :
                lane == 6 ? w12 : w13;
        msk[prow + rr][lane] = v;
      }
    }
  }
  __syncthreads();   // masks + G1/G2 visible to all waves

  // ---- consume phase
  f32x4 acc[2][4];
  #pragma unroll
  for (int mt = 0; mt < 2; mt++)
    #pragma unroll
    for (int nt = 0; nt < 4; nt++) acc[mt][nt] = (f32x4){0.f, 0.f, 0.f, 0.f};
  float psum[2] = {0.f, 0.f};

  const int r0l = p * 32 + m;
  const __bf16* bsrc_base = Bp + (size_t)ks * 16 * 4096 + (size_t)nh * 4 * 512 + lane * 8;

  for (int sg = 0; sg < SGN; ++sg) {        // one 256-col group per sg
    u64x2 Ma01 = *(const u64x2*)&msk[r0l][sg * 4];
    u64x2 Ma23 = *(const u64x2*)&msk[r0l][sg * 4 + 2];
    u64x2 Mb01 = *(const u64x2*)&msk[r0l + 16][sg * 4];
    u64x2 Mb23 = *(const u64x2*)&msk[r0l + 16][sg * 4 + 2];

    #pragma unroll
    for (int ss = 0; ss < 4; ++ss) {
      const int step = sg * 4 + ss;
      #pragma unroll
      for (int kg = 0; kg < 2; kg++) {
        const int jj = step * 64 + kg * 32 + q * 8;
        float4 u0 = *(const float4*)(G1 + jj);
        float4 u1 = *(const float4*)(G1 + jj + 4);
        float4 v0 = *(const float4*)(G2 + jj);
        float4 v1 = *(const float4*)(G2 + jj + 4);
        const unsigned b = ss * 16 + kg * 8 + q * 2;   // bit pos (<=62)

        bf16x8 af[2];
        #pragma unroll
        for (int mt = 0; mt < 2; mt++) {
          const u64 M0 = mt ? Mb01[0] : Ma01[0];
          const u64 M1 = mt ? Mb01[1] : Ma01[1];
          const u64 M2 = mt ? Mb23[0] : Ma23[0];
          const u64 M3 = mt ? Mb23[1] : Ma23[1];
          const unsigned e0 = (unsigned)(M0 >> b);
          const unsigned e1 = (unsigned)(M1 >> b);
          const unsigned e2 = (unsigned)(M2 >> b);
          const unsigned e3 = (unsigned)(M3 >> b);
          const float f1 = F1[mt], f2 = F2[mt];
          float p0 = (e0 & 1u) ? fmaxf(f1 * u0.x, f2 * v0.x) : 0.f;
          float p1 = (e1 & 1u) ? fmaxf(f1 * u0.y, f2 * v0.y) : 0.f;
          float p2 = (e2 & 1u) ? fmaxf(f1 * u0.z, f2 * v0.z) : 0.f;
          float p3 = (e3 & 1u) ? fmaxf(f1 * u0.w, f2 * v0.w) : 0.f;
          float p4 = (e0 & 2u) ? fmaxf(f1 * u1.x, f2 * v1.x) : 0.f;
          float p5 = (e1 & 2u) ? fmaxf(f1 * u1.y, f2 * v1.y) : 0.f;
          float p6 = (e2 & 2u) ? fmaxf(f1 * u1.z, f2 * v1.z) : 0.f;
          float p7 = (e3 & 2u) ? fmaxf(f1 * u1.w, f2 * v1.w) : 0.f;
          if (nh == 0)
            psum[mt] += ((p0 + p1) + (p2 + p3)) + ((p4 + p5) + (p6 + p7));
          bf16x8 a;
          a[0] = (__bf16)p0; a[1] = (__bf16)p1; a[2] = (__bf16)p2;
          a[3] = (__bf16)p3; a[4] = (__bf16)p4; a[5] = (__bf16)p5;
          a[6] = (__bf16)p6; a[7] = (__bf16)p7;
          af[mt] = a;
        }

        const __bf16* bsrc = bsrc_base + (size_t)(step * 2 + kg) * 4096;
        #pragma unroll
        for (int nt = 0; nt < 4; nt++) {
          bf16x8 bfrag = *(const bf16x8*)(bsrc + nt * 512);
          acc[0][nt] = __builtin_amdgcn_mfma_f32_16x16x32_bf16(af[0], bfrag, acc[0][nt], 0, 0, 0);
          acc[1][nt] = __builtin_amdgcn_mfma_f32_16x16x32_bf16(af[1], bfrag, acc[1][nt], 0, 0, 0);
        }
      }
    }
  }

  // denominator partials: only the nh==0 wave of each row-pair writes
  // (p values are identical across the nt-split).
  if (nh == 0) {
    float* ldst = lpart + (size_t)ks * NN;
    #pragma unroll
    for (int mt = 0; mt < 2; mt++) {
      float pp = psum[mt];
      pp += __shfl_xor(pp, 16);
      pp += __shfl_xor(pp, 32);
      if (lane < 16) ldst[wbase + mt * 16 + lane] = pp;
    }
  }

  // numerator partials: C/D layout row=q*4+r, col=(nh*4+nt)*16+m; plain
  // stores — each (ks,row,col) element owned by exactly one lane.
  float* pdst = part + (size_t)ks * NN * FO;
  #pragma unroll
  for (int mt = 0; mt < 2; mt++) {
    const int rb0 = wbase + mt * 16 + q * 4;
    #pragma unroll
    for (int nt = 0; nt < 4; nt++) {
      #pragma unroll
      for (int r = 0; r < 4; r++) {
        pdst[(size_t)(rb0 + r) * FO + (nh * 4 + nt) * 16 + m] = acc[mt][nt][r];
      }
    }
  }
}

// ---------------------------------------------------------------------------
// Kernel 3: out = (sum_ks part) / (sum_ks lpart), vectorized float4.
// EXACTLY 262144 float4 outputs -> grid 1024 x 256.
// ---------------------------------------------------------------------------
__global__ __launch_bounds__(256) void k_div(
    const float* __restrict__ part, const float* __restrict__ lpart,
    float* __restrict__ out)
{
  int idx = blockIdx.x * 256 + threadIdx.x;        // float4 index (262144 total)
  int row = idx >> 5;                              // 32 float4 per row
  float4 s = {0.f, 0.f, 0.f, 0.f};
  float l = 0.f;
  #pragma unroll
  for (int ks = 0; ks < KSPLIT; ks++) {
    float4 v = ((const float4*)(part + (size_t)ks * NN * FO))[idx];
    s.x += v.x; s.y += v.y; s.z += v.z; s.w += v.w;
    l += lpart[ks * NN + row];
  }
  float inv = 1.0f / l;
  float4 o;
  o.x = s.x * inv; o.y = s.y * inv; o.z = s.z * inv; o.w = s.w * inv;
  ((float4*)out)[idx] = o;
}

extern "C" void kernel_launch(void* const* d_in, const int* in_sizes, int n_in,
                              void* d_out, int out_size, void* d_ws, size_t ws_size,
                              hipStream_t stream) {
  const float* x     = (const float*)d_in[0];
  const float* adj   = (const float*)d_in[1];
  const float* W     = (const float*)d_in[2];
  const float* a_src = (const float*)d_in[3];
  const float* a_dst = (const float*)d_in[4];
  float* out = (float*)d_out;

  char* ws = (char*)d_ws;
  __bf16* Bp   = (__bf16*)ws;                      // 0 .. 2 MB
  float* f_src = (float*)(ws + 2097152);           // 32 KB
  float* f_dst = (float*)(ws + 2097152 + 32768);   // 32 KB
  float* part  = (float*)(ws + 16777216);          // 16 MB .. 80 MB (16 x 4 MB)
  float* lpart = (float*)(ws + 83886080);          // 80 MB .. +512 KB

  // No memset needed: part/lpart/out are fully written.
  hipLaunchKernelGGL(k_proj, dim3(512), dim3(256), 0, stream,
                     x, W, a_src, a_dst, Bp, f_src, f_dst);
  hipLaunchKernelGGL(k_attn, dim3(2048), dim3(256), 0, stream,
                     adj, Bp, f_src, f_dst, part, lpart);
  hipLaunchKernelGGL(k_div, dim3(1024), dim3(256), 0, stream,
                     part, lpart, out);
}